// Round 1
// baseline (551.812 us; speedup 1.0000x reference)
//
#include <hip/hip_runtime.h>
#include <hip/hip_bf16.h>

#define IN_F 4096
#define OUT_F 4096
#define M_ROWS 8192          // 4 * 2048
#define GROUP 128

#define BM 128
#define BN 128
#define BK 32

typedef __attribute__((ext_vector_type(8))) short short8;
typedef __attribute__((ext_vector_type(4))) float floatx4;

__device__ __forceinline__ unsigned short f2bf(float f) {
    unsigned int u = __builtin_bit_cast(unsigned int, f);
    u += 0x7fffu + ((u >> 16) & 1u);   // round-to-nearest-even (no NaN inputs here)
    return (unsigned short)(u >> 16);
}

__device__ __forceinline__ void load_lds16(const unsigned short* g, unsigned short* l) {
    __builtin_amdgcn_global_load_lds(
        (const __attribute__((address_space(1))) void*)g,
        (__attribute__((address_space(3))) void*)l,
        16, 0, 0);
}

// ---------------------------------------------------------------------------
// Kernel 1: x fp32 -> bf16, 8 elements/thread
// ---------------------------------------------------------------------------
__global__ __launch_bounds__(256) void convert_x_kernel(const float* __restrict__ x,
                                                        unsigned short* __restrict__ xb) {
    size_t t = (size_t)blockIdx.x * 256 + threadIdx.x;   // t in [0, 8192*4096/8)
    const float4* src = (const float4*)x + t * 2;
    float4 a = src[0];
    float4 b = src[1];
    union { unsigned short us[8]; uint4 v; } o;
    o.us[0] = f2bf(a.x); o.us[1] = f2bf(a.y); o.us[2] = f2bf(a.z); o.us[3] = f2bf(a.w);
    o.us[4] = f2bf(b.x); o.us[5] = f2bf(b.y); o.us[6] = f2bf(b.z); o.us[7] = f2bf(b.w);
    ((uint4*)xb)[t] = o.v;
}

// ---------------------------------------------------------------------------
// Kernel 2: dequant -> W^T bf16  [OUT_F][IN_F]   (wt[n][k])
// thread t: n = t>>9, kp = t&511  (kp indexes the packed int32 along K)
// wave (64 consecutive kp, same n) writes contiguous 1 KB -> coalesced stores
// ---------------------------------------------------------------------------
__global__ __launch_bounds__(256) void dequant_kernel(const int* __restrict__ qw,
                                                      const int* __restrict__ qz,
                                                      const float* __restrict__ sc,
                                                      unsigned short* __restrict__ wt) {
    int t = blockIdx.x * 256 + threadIdx.x;   // [0, 4096*512)
    int n  = t >> 9;
    int kp = t & 511;
    int g  = kp >> 4;                          // k-group = (kp*8)/128
    unsigned q  = (unsigned)qw[kp * OUT_F + n];
    unsigned zq = (unsigned)qz[g * (OUT_F / 8) + (n >> 3)];
    float zero = (float)(((zq >> ((n & 7) * 4)) & 15u) + 1u);
    float s = sc[g * OUT_F + n];
    union { unsigned short us[8]; uint4 v; } o;
#pragma unroll
    for (int j = 0; j < 8; ++j) {
        float w = (float)((q >> (4 * j)) & 15u);
        o.us[j] = f2bf(s * (w - zero));
    }
    *((uint4*)(wt + ((size_t)n * IN_F + kp * 8))) = o.v;
}

// ---------------------------------------------------------------------------
// Kernel 3: bf16 MFMA GEMM (m97 structure)
//   C[M_ROWS, OUT_F] = xb[M_ROWS, IN_F] * wt[OUT_F, IN_F]^T + bias
//   128x128 tile, BK=32, 256 threads = 4 waves (2x2), 4x4 16x16x32 MFMAs/wave
// ---------------------------------------------------------------------------
__global__ __launch_bounds__(256) void gemm_kernel(const unsigned short* __restrict__ xb,
                                                   const unsigned short* __restrict__ wt,
                                                   const float* __restrict__ bias,
                                                   float* __restrict__ out) {
    __shared__ unsigned short As[BM * BK];   // [row][k] row-major, 8 KB
    __shared__ unsigned short Bs[BN * BK];   // [col][k] row-major, 8 KB

    const int tid  = threadIdx.x;
    const int wid  = tid >> 6;
    const int lane = tid & 63;
    const int m0 = blockIdx.y * BM;
    const int n0 = blockIdx.x * BN;
    const int wave_m = wid & 1;
    const int wave_n = wid >> 1;

    floatx4 acc[4][4] = {};

    // staging: chunk = r*4 + wid covers 16 rows (1 KB); lane i -> row i/4, k (i%4)*8
    const int srow = lane >> 2;
    const int skq  = (lane & 3) * 8;
    const unsigned short* ga0 = xb + (size_t)(m0 + (wid + 0) * 16 + srow) * IN_F + skq;
    const unsigned short* ga1 = xb + (size_t)(m0 + (wid + 4) * 16 + srow) * IN_F + skq;
    const unsigned short* gb0 = wt + (size_t)(n0 + (wid + 0) * 16 + srow) * IN_F + skq;
    const unsigned short* gb1 = wt + (size_t)(n0 + (wid + 4) * 16 + srow) * IN_F + skq;
    unsigned short* la0 = &As[(wid + 0) * 512];
    unsigned short* la1 = &As[(wid + 4) * 512];
    unsigned short* lb0 = &Bs[(wid + 0) * 512];
    unsigned short* lb1 = &Bs[(wid + 4) * 512];

    // fragment read offsets (elements): row = (lane&15), k-off = (lane>>4)*8
    const int afo = (wave_m * 64 + (lane & 15)) * BK + (lane >> 4) * 8;
    const int bfo = (wave_n * 64 + (lane & 15)) * BK + (lane >> 4) * 8;

    for (int kt = 0; kt < IN_F; kt += BK) {
        __syncthreads();
        load_lds16(ga0 + kt, la0);
        load_lds16(ga1 + kt, la1);
        load_lds16(gb0 + kt, lb0);
        load_lds16(gb1 + kt, lb1);
        __syncthreads();

        short8 a[4], b[4];
#pragma unroll
        for (int i = 0; i < 4; ++i)
            a[i] = *(const short8*)&As[afo + i * 16 * BK];
#pragma unroll
        for (int j = 0; j < 4; ++j)
            b[j] = *(const short8*)&Bs[bfo + j * 16 * BK];
#pragma unroll
        for (int i = 0; i < 4; ++i)
#pragma unroll
            for (int j = 0; j < 4; ++j)
                acc[i][j] = __builtin_amdgcn_mfma_f32_16x16x32_bf16(a[i], b[j], acc[i][j], 0, 0, 0);
    }

    // epilogue: C/D layout col = lane&15, row = (lane>>4)*4 + reg
    const int mrow = m0 + wave_m * 64 + (lane >> 4) * 4;
    const int ncol = n0 + wave_n * 64 + (lane & 15);
#pragma unroll
    for (int j = 0; j < 4; ++j) {
        const int n = ncol + j * 16;
        const float bv = bias[n];
#pragma unroll
        for (int i = 0; i < 4; ++i) {
            const int m = mrow + i * 16;
#pragma unroll
            for (int r = 0; r < 4; ++r)
                out[(size_t)(m + r) * OUT_F + n] = acc[i][j][r] + bv;
        }
    }
}

extern "C" void kernel_launch(void* const* d_in, const int* in_sizes, int n_in,
                              void* d_out, int out_size, void* d_ws, size_t ws_size,
                              hipStream_t stream) {
    const float* x    = (const float*)d_in[0];
    const int*   qw   = (const int*)d_in[1];
    const int*   qz   = (const int*)d_in[2];
    const float* sc   = (const float*)d_in[3];
    const float* bias = (const float*)d_in[4];
    float* out = (float*)d_out;

    unsigned short* xb = (unsigned short*)d_ws;                       // 64 MiB
    unsigned short* wt = xb + (size_t)M_ROWS * IN_F;                  // +32 MiB

    convert_x_kernel<<<(M_ROWS * IN_F / 8) / 256, 256, 0, stream>>>(x, xb);
    dequant_kernel<<<(OUT_F * (IN_F / 8)) / 256, 256, 0, stream>>>(qw, qz, sc, wt);
    gemm_kernel<<<dim3(OUT_F / BN, M_ROWS / BM), 256, 0, stream>>>(xb, wt, bias, out);
}

// Round 2
// 535.381 us; speedup vs baseline: 1.0307x; 1.0307x over previous
//
#include <hip/hip_runtime.h>
#include <hip/hip_bf16.h>

#define IN_F 4096
#define OUT_F 4096
#define M_ROWS 8192          // 4 * 2048
#define GROUP 128

#define BM 128
#define BN 128
#define BK 32

typedef __attribute__((ext_vector_type(8))) short short8;
typedef __attribute__((ext_vector_type(4))) float floatx4;

__device__ __forceinline__ unsigned short f2bf(float f) {
    unsigned int u = __builtin_bit_cast(unsigned int, f);
    u += 0x7fffu + ((u >> 16) & 1u);   // round-to-nearest-even (no NaN inputs here)
    return (unsigned short)(u >> 16);
}

__device__ __forceinline__ void load_lds16(const unsigned short* g, unsigned short* l) {
    __builtin_amdgcn_global_load_lds(
        (const __attribute__((address_space(1))) void*)g,
        (__attribute__((address_space(3))) void*)l,
        16, 0, 0);
}

// ---------------------------------------------------------------------------
// Kernel 1: x fp32 -> bf16, 8 elements/thread (coalesced both sides)
// ---------------------------------------------------------------------------
__global__ __launch_bounds__(256) void convert_x_kernel(const float* __restrict__ x,
                                                        unsigned short* __restrict__ xb) {
    size_t t = (size_t)blockIdx.x * 256 + threadIdx.x;   // t in [0, 8192*4096/8)
    const float4* src = (const float4*)x + t * 2;
    float4 a = src[0];
    float4 b = src[1];
    union { unsigned short us[8]; uint4 v; } o;
    o.us[0] = f2bf(a.x); o.us[1] = f2bf(a.y); o.us[2] = f2bf(a.z); o.us[3] = f2bf(a.w);
    o.us[4] = f2bf(b.x); o.us[5] = f2bf(b.y); o.us[6] = f2bf(b.z); o.us[7] = f2bf(b.w);
    ((uint4*)xb)[t] = o.v;
}

// ---------------------------------------------------------------------------
// Kernel 2: dequant -> W^T bf16  [OUT_F][IN_F]  via LDS transpose.
// Tile: 32 kp (=256 k) x 64 n. Grid: (512/32, 4096/64) = (16, 64).
//
// Phase 1 (coalesced read): thread t -> kp_l = t>>3, nq = t&7.
//   Reads qw[kp][n0+nq*8 .. +7] (32 B contiguous per thread; wave = 8 rows
//   x 256 B segments). Dequants 8n x 8k, writes short8 rows into LDS tile
//   laid out [n][k] (row = 256 k elements = 512 B).
// Phase 2 (coalesced write): pass p, thread t -> n_l = p*8 + (t>>5),
//   chunk = t&31. Wave writes 2 n-rows x 512 B contiguous each.
// ---------------------------------------------------------------------------
#define DQ_KP 32
#define DQ_N  64

__global__ __launch_bounds__(256) void dequant_kernel(const int* __restrict__ qw,
                                                      const int* __restrict__ qz,
                                                      const float* __restrict__ sc,
                                                      unsigned short* __restrict__ wt) {
    __shared__ unsigned short tile[DQ_N * DQ_KP * 8];   // 64 * 256 * 2 B = 32 KB

    const int t   = threadIdx.x;
    const int kp0 = blockIdx.x * DQ_KP;
    const int n0  = blockIdx.y * DQ_N;

    // ---- phase 1: read + dequant + LDS ----
    {
        const int kp_l = t >> 3;            // 0..31
        const int nq   = t & 7;             // which 8-n chunk
        const int kp   = kp0 + kp_l;
        const int g    = kp >> 4;           // k-group (GROUP=128 = 16 kp)
        const int nb   = n0 + nq * 8;

        const uint4 q0 = *(const uint4*)&qw[(size_t)kp * OUT_F + nb];
        const uint4 q1 = *(const uint4*)&qw[(size_t)kp * OUT_F + nb + 4];
        const unsigned zq = (unsigned)qz[g * (OUT_F / 8) + (nb >> 3)];
        const float4 s0 = *(const float4*)&sc[(size_t)g * OUT_F + nb];
        const float4 s1 = *(const float4*)&sc[(size_t)g * OUT_F + nb + 4];

        unsigned qv[8] = {q0.x, q0.y, q0.z, q0.w, q1.x, q1.y, q1.z, q1.w};
        float    sv[8] = {s0.x, s0.y, s0.z, s0.w, s1.x, s1.y, s1.z, s1.w};

#pragma unroll
        for (int c = 0; c < 8; ++c) {
            const unsigned q = qv[c];
            const float zero = (float)(((zq >> (4 * c)) & 15u) + 1u);
            const float s = sv[c];
            union { unsigned short us[8]; uint4 v; } o;
#pragma unroll
            for (int j = 0; j < 8; ++j) {
                const float w = (float)((q >> (4 * j)) & 15u);
                o.us[j] = f2bf(s * (w - zero));
            }
            *(uint4*)&tile[(nq * 8 + c) * (DQ_KP * 8) + kp_l * 8] = o.v;
        }
    }

    __syncthreads();

    // ---- phase 2: LDS -> global, coalesced along k ----
    {
        const int chunk = t & 31;           // 16 B chunk within the 256-k row
        const int nw    = t >> 5;           // 0..7
#pragma unroll
        for (int p = 0; p < 8; ++p) {
            const int n_l = p * 8 + nw;
            const uint4 v = *(const uint4*)&tile[n_l * (DQ_KP * 8) + chunk * 8];
            *(uint4*)&wt[(size_t)(n0 + n_l) * IN_F + kp0 * 8 + chunk * 8] = v;
        }
    }
}

// ---------------------------------------------------------------------------
// Kernel 3: bf16 MFMA GEMM (m97 structure) — unchanged from round 1
//   C[M_ROWS, OUT_F] = xb[M_ROWS, IN_F] * wt[OUT_F, IN_F]^T + bias
// ---------------------------------------------------------------------------
__global__ __launch_bounds__(256) void gemm_kernel(const unsigned short* __restrict__ xb,
                                                   const unsigned short* __restrict__ wt,
                                                   const float* __restrict__ bias,
                                                   float* __restrict__ out) {
    __shared__ unsigned short As[BM * BK];   // [row][k] row-major, 8 KB
    __shared__ unsigned short Bs[BN * BK];   // [col][k] row-major, 8 KB

    const int tid  = threadIdx.x;
    const int wid  = tid >> 6;
    const int lane = tid & 63;
    const int m0 = blockIdx.y * BM;
    const int n0 = blockIdx.x * BN;
    const int wave_m = wid & 1;
    const int wave_n = wid >> 1;

    floatx4 acc[4][4] = {};

    const int srow = lane >> 2;
    const int skq  = (lane & 3) * 8;
    const unsigned short* ga0 = xb + (size_t)(m0 + (wid + 0) * 16 + srow) * IN_F + skq;
    const unsigned short* ga1 = xb + (size_t)(m0 + (wid + 4) * 16 + srow) * IN_F + skq;
    const unsigned short* gb0 = wt + (size_t)(n0 + (wid + 0) * 16 + srow) * IN_F + skq;
    const unsigned short* gb1 = wt + (size_t)(n0 + (wid + 4) * 16 + srow) * IN_F + skq;
    unsigned short* la0 = &As[(wid + 0) * 512];
    unsigned short* la1 = &As[(wid + 4) * 512];
    unsigned short* lb0 = &Bs[(wid + 0) * 512];
    unsigned short* lb1 = &Bs[(wid + 4) * 512];

    const int afo = (wave_m * 64 + (lane & 15)) * BK + (lane >> 4) * 8;
    const int bfo = (wave_n * 64 + (lane & 15)) * BK + (lane >> 4) * 8;

    for (int kt = 0; kt < IN_F; kt += BK) {
        __syncthreads();
        load_lds16(ga0 + kt, la0);
        load_lds16(ga1 + kt, la1);
        load_lds16(gb0 + kt, lb0);
        load_lds16(gb1 + kt, lb1);
        __syncthreads();

        short8 a[4], b[4];
#pragma unroll
        for (int i = 0; i < 4; ++i)
            a[i] = *(const short8*)&As[afo + i * 16 * BK];
#pragma unroll
        for (int j = 0; j < 4; ++j)
            b[j] = *(const short8*)&Bs[bfo + j * 16 * BK];
#pragma unroll
        for (int i = 0; i < 4; ++i)
#pragma unroll
            for (int j = 0; j < 4; ++j)
                acc[i][j] = __builtin_amdgcn_mfma_f32_16x16x32_bf16(a[i], b[j], acc[i][j], 0, 0, 0);
    }

    // epilogue: C/D layout col = lane&15, row = (lane>>4)*4 + reg
    const int mrow = m0 + wave_m * 64 + (lane >> 4) * 4;
    const int ncol = n0 + wave_n * 64 + (lane & 15);
#pragma unroll
    for (int j = 0; j < 4; ++j) {
        const int n = ncol + j * 16;
        const float bv = bias[n];
#pragma unroll
        for (int i = 0; i < 4; ++i) {
            const int m = mrow + i * 16;
#pragma unroll
            for (int r = 0; r < 4; ++r)
                out[(size_t)(m + r) * OUT_F + n] = acc[i][j][r] + bv;
        }
    }
}

extern "C" void kernel_launch(void* const* d_in, const int* in_sizes, int n_in,
                              void* d_out, int out_size, void* d_ws, size_t ws_size,
                              hipStream_t stream) {
    const float* x    = (const float*)d_in[0];
    const int*   qw   = (const int*)d_in[1];
    const int*   qz   = (const int*)d_in[2];
    const float* sc   = (const float*)d_in[3];
    const float* bias = (const float*)d_in[4];
    float* out = (float*)d_out;

    unsigned short* xb = (unsigned short*)d_ws;                       // 64 MiB
    unsigned short* wt = xb + (size_t)M_ROWS * IN_F;                  // +32 MiB

    convert_x_kernel<<<(M_ROWS * IN_F / 8) / 256, 256, 0, stream>>>(x, xb);
    dequant_kernel<<<dim3(IN_F / 8 / DQ_KP, OUT_F / DQ_N), 256, 0, stream>>>(qw, qz, sc, wt);
    gemm_kernel<<<dim3(OUT_F / BN, M_ROWS / BM), 256, 0, stream>>>(xb, wt, bias, out);
}